// Round 6
// baseline (79.077 us; speedup 1.0000x reference)
//
#include <hip/hip_runtime.h>
#include <hip/hip_bf16.h>

#define EPS 1e-6f

typedef __attribute__((ext_vector_type(4))) float f32x4;
typedef __attribute__((ext_vector_type(4))) int i32x4;
typedef __attribute__((ext_vector_type(8))) int i32x8;

// pack 4 floats into 4 fp8-e4m3 bytes (k-order: x->byte0 .. w->byte3)
__device__ inline unsigned int pack_fp8x4(float x, float y, float z, float w) {
  int r = 0;
  r = __builtin_amdgcn_cvt_pk_fp8_f32(x, y, r, false);  // bytes 0,1
  r = __builtin_amdgcn_cvt_pk_fp8_f32(z, w, r, true);   // bytes 2,3
  return (unsigned int)r;
}

// ---------------------------------------------------------------------------
// Kernel A: per-speaker precompute (192 threads, float4-vectorized).
// Writes: a8[i][d] = fp8e4m3(dvec[i][d]/||dvec_i||)      (10240 x 768, 7.9 MB)
//         c8[n][d] = fp8e4m3(ctrd[n][d]/||ctrd_n||)      (1024 x 768)
//         simown[i] = fp32 cosine(dvec_i, excl-centroid) (10240)
// Also zeroes rowsum[10240] and out[0].
// ---------------------------------------------------------------------------
__global__ void __launch_bounds__(192) ge2e_pre(
    const float* __restrict__ dv, unsigned int* __restrict__ a8u,
    unsigned int* __restrict__ c8u, float* __restrict__ simown,
    float* __restrict__ rowsum, float* __restrict__ out) {
  const int n = blockIdx.x, t = threadIdx.x;  // t in [0,192): owns dims 4t..4t+3
  if (n == 0 && t == 0) out[0] = 0.f;  // consumed by ge2e_final (stream-ordered)
  const float* base = dv + (size_t)n * 7680;
  float4 v[10];
  float4 s4 = make_float4(0.f, 0.f, 0.f, 0.f);
#pragma unroll
  for (int m = 0; m < 10; ++m) {
    v[m] = *reinterpret_cast<const float4*>(&base[m * 768 + 4 * t]);
    s4.x += v[m].x; s4.y += v[m].y; s4.z += v[m].z; s4.w += v[m].w;
  }
  float part[21];
#pragma unroll
  for (int m = 0; m < 10; ++m) {
    part[m]      = v[m].x * s4.x + v[m].y * s4.y + v[m].z * s4.z + v[m].w * s4.w;
    part[10 + m] = v[m].x * v[m].x + v[m].y * v[m].y + v[m].z * v[m].z + v[m].w * v[m].w;
  }
  part[20] = s4.x * s4.x + s4.y * s4.y + s4.z * s4.z + s4.w * s4.w;
#pragma unroll
  for (int k = 0; k < 21; ++k) {
#pragma unroll
    for (int off = 32; off >= 1; off >>= 1) part[k] += __shfl_xor(part[k], off);
  }
  __shared__ float red[3][21];
  __shared__ float bc[21];
  const int lane = t & 63, wid = t >> 6;
  if (lane == 0) {
#pragma unroll
    for (int k = 0; k < 21; ++k) red[wid][k] = part[k];
  }
  __syncthreads();
  if (t < 21) bc[t] = red[0][t] + red[1][t] + red[2][t];
  __syncthreads();
  const float ss = bc[20];
  // centroid = sums/10; cnorm = max(|ctrd|,eps) -> normalize sums by max(|sums|,10eps)
  const float rc = 1.0f / fmaxf(sqrtf(ss), 10.0f * EPS);
  c8u[n * 192 + t] = pack_fp8x4(s4.x * rc, s4.y * rc, s4.z * rc, s4.w * rc);
#pragma unroll
  for (int m = 0; m < 10; ++m) {
    float rd = 1.0f / fmaxf(sqrtf(bc[10 + m]), EPS);
    a8u[(size_t)(n * 10 + m) * 192 + t] =
        pack_fp8x4(v[m].x * rd, v[m].y * rd, v[m].z * rd, v[m].w * rd);
  }
  if (t < 10) {
    float dot = bc[t], sq = bc[10 + t];
    float dn = fmaxf(sqrtf(sq), EPS);
    float en = fmaxf(sqrtf(fmaxf(ss - 2.f * dot + sq, 0.f)) * (1.0f / 9.0f), EPS);
    simown[n * 10 + t] = ((dot - sq) * (1.0f / 9.0f)) / (dn * en);
    rowsum[n * 10 + t] = 0.f;  // accumulated by ge2e_gemm atomics
  }
}

// ---------------------------------------------------------------------------
// Kernel B: MX-fp8 MFMA GEMM (10240x1024x768) fused with diagonal replacement
// and direct exp-sum accumulation.
// Round-6 structure: 64x128 tile, BK=128 via mfma_scale_f32_16x16x128_f8f6f4
// (scales = 1.0 -> plain fp8 GEMM at 2x bf16 rate), only SIX K-steps.
// Double-buffered LDS (48 KB -> 3 blocks/CU), depth-1 prefetch +
// vmcnt(0)/s_barrier per K-step. LDS rows are 128 B; 16B-chunk XOR-8 swizzle
// (slot = kc ^ (row&7)) applied to BOTH the global_load_lds source address
// and the ds_read address -> frag reads are ~conflict-free (2-way).
// 1280 blocks, bijective XCD swizzle (1280 = 8 x 160).
// ---------------------------------------------------------------------------
__global__ void __launch_bounds__(256, 3) ge2e_gemm(
    const unsigned char* __restrict__ a8, const unsigned char* __restrict__ c8,
    const float* __restrict__ simown, const float* __restrict__ wp,
    float* __restrict__ rowsum) {
  __shared__ unsigned char As[2][64 * 128];    // 8 KB per buffer
  __shared__ unsigned char Bs[2][128 * 128];   // 16 KB per buffer
  const int t = threadIdx.x;
  const int lane = t & 63, wid = t >> 6;
  const int bx = blockIdx.x;
  const int wg = (bx & 7) * 160 + (bx >> 3);  // bijective XCD swizzle
  const int rb = wg >> 3, cb = wg & 7;
  const int row0 = rb * 64, col0 = cb * 128;
  const int wr = wid >> 1, wc = wid & 1;       // wave tile: 32 rows x 64 cols
  const int l15 = lane & 15, lg = lane >> 4;

  f32x4 acc[2][4];
#pragma unroll
  for (int i = 0; i < 2; ++i)
#pragma unroll
    for (int j = 0; j < 4; ++j) acc[i][j] = (f32x4){0.f, 0.f, 0.f, 0.f};

  // Stage A (512 x 16B chunks) + B (1024 chunks) for K-slab kk (bytes == elems).
  // LDS chunk c holds global k-chunk (c&7)^(row&7) of row c>>3 (XOR-8 swizzle).
  auto STAGE = [&](int buf, int kk) {
#pragma unroll
    for (int jj = 0; jj < 2; ++jj) {
      const int c = (wid * 2 + jj) * 64 + lane;
      const int row = c >> 3, kc = (c & 7) ^ (row & 7);
      const unsigned char* src = a8 + (size_t)(row0 + row) * 768 + kk + kc * 16;
      unsigned char* dst = &As[buf][(wid * 2 + jj) * 1024];  // + lane*16 by HW
      __builtin_amdgcn_global_load_lds(
          (const __attribute__((address_space(1))) unsigned int*)src,
          (__attribute__((address_space(3))) unsigned int*)dst, 16, 0, 0);
    }
#pragma unroll
    for (int jj = 0; jj < 4; ++jj) {
      const int c = (wid * 4 + jj) * 64 + lane;
      const int row = c >> 3, kc = (c & 7) ^ (row & 7);
      const unsigned char* src = c8 + (size_t)(col0 + row) * 768 + kk + kc * 16;
      unsigned char* dst = &Bs[buf][(wid * 4 + jj) * 1024];
      __builtin_amdgcn_global_load_lds(
          (const __attribute__((address_space(1))) unsigned int*)src,
          (__attribute__((address_space(3))) unsigned int*)dst, 16, 0, 0);
    }
  };
  // Read one 32-byte k-run fragment (two swizzled 16B chunks) from LDS.
  auto READ_FRAG = [&](const unsigned char* base, int row) -> i32x8 {
    const int r7 = row & 7;
    const unsigned char* rp = base + row * 128;
    i32x4 lo = *(const i32x4*)(rp + (((lg * 2) ^ r7) * 16));
    i32x4 hi = *(const i32x4*)(rp + (((lg * 2 + 1) ^ r7) * 16));
    i32x8 v;
#pragma unroll
    for (int q = 0; q < 4; ++q) { v[q] = lo[q]; v[q + 4] = hi[q]; }
    return v;
  };
  auto COMPUTE = [&](int buf) {
    i32x8 af[2], bq[4];
#pragma unroll
    for (int i = 0; i < 2; ++i)
      af[i] = READ_FRAG(As[buf], wr * 32 + i * 16 + l15);
#pragma unroll
    for (int j = 0; j < 4; ++j)
      bq[j] = READ_FRAG(Bs[buf], wc * 64 + j * 16 + l15);
#pragma unroll
    for (int i = 0; i < 2; ++i)
#pragma unroll
      for (int j = 0; j < 4; ++j)
        acc[i][j] = __builtin_amdgcn_mfma_scale_f32_16x16x128_f8f6f4(
            af[i], bq[j], acc[i][j], 0 /*cbsz: fp8*/, 0 /*blgp: fp8*/,
            0, 0x7f7f7f7f /*scaleA = 1.0*/, 0, 0x7f7f7f7f /*scaleB = 1.0*/);
  };

  // prologue
  STAGE(0, 0);
  asm volatile("s_waitcnt vmcnt(0)" ::: "memory");
  __builtin_amdgcn_s_barrier();
  int cur = 0;
  for (int tt = 0; tt < 5; ++tt) {   // 6 K-slabs of 128
    STAGE(cur ^ 1, (tt + 1) * 128);
    COMPUTE(cur);  // lgkmcnt deps force ds_reads done before barrier
    asm volatile("s_waitcnt vmcnt(0)" ::: "memory");
    __builtin_amdgcn_s_barrier();
    cur ^= 1;
  }
  COMPUTE(cur);

  // Epilogue: vv = w*cos (diagonal: fp32 sim_own); rowsum[grow] += sum_j exp(vv)
  // |vv| <= ~10.1 -> exp fp32-safe without max subtraction; bias b cancels.
  const float wv = wp[0];
  const int R0 = row0 + wr * 32, C0 = col0 + wc * 64;
#pragma unroll
  for (int i = 0; i < 2; ++i) {
#pragma unroll
    for (int r = 0; r < 4; ++r) {
      const int grow = R0 + i * 16 + lg * 4 + r;
      const int ownc = grow / 10;  // own speaker column
      float sm = 0.f;
#pragma unroll
      for (int j = 0; j < 4; ++j) {
        const int gcol = C0 + j * 16 + l15;
        float vv = wv * acc[i][j][r];
        if (gcol == ownc) vv = wv * simown[grow];
        sm += __expf(vv);
      }
#pragma unroll
      for (int off = 1; off < 16; off <<= 1) sm += __shfl_xor(sm, off, 16);
      if (l15 == 0) atomicAdd(&rowsum[grow], sm);
    }
  }
}

// ---------------------------------------------------------------------------
// Kernel C: loss_i = log(rowsum_i) - w*simown_i; sum over 10240 into d_out.
// ---------------------------------------------------------------------------
__global__ void __launch_bounds__(256) ge2e_final(
    const float* __restrict__ rowsum, const float* __restrict__ simown,
    const float* __restrict__ wp, float* __restrict__ out) {
  const int i = blockIdx.x * 256 + threadIdx.x;  // 0..10239
  const float wv = wp[0];
  float loss = logf(rowsum[i]) - wv * simown[i];
#pragma unroll
  for (int off = 32; off >= 1; off >>= 1) loss += __shfl_xor(loss, off);
  __shared__ float red[4];
  const int lane = threadIdx.x & 63, wid = threadIdx.x >> 6;
  if (lane == 0) red[wid] = loss;
  __syncthreads();
  if (threadIdx.x == 0) atomicAdd(out, red[0] + red[1] + red[2] + red[3]);
}

extern "C" void kernel_launch(void* const* d_in, const int* in_sizes, int n_in,
                              void* d_out, int out_size, void* d_ws, size_t ws_size,
                              hipStream_t stream) {
  (void)in_sizes; (void)n_in; (void)out_size; (void)ws_size;
  const float* dv = (const float*)d_in[0];
  const float* wp = (const float*)d_in[1];
  // d_in[2] (bias b) cancels exactly in -log_softmax[own]; unused.

  unsigned char* a8 = (unsigned char*)d_ws;                         // 7,864,320 B
  unsigned char* c8 = (unsigned char*)d_ws + 7864320;               //   786,432 B
  float* simown = (float*)((char*)d_ws + 8650752);                  //    40,960 B
  float* rowsum = (float*)((char*)d_ws + 8691712);                  //    40,960 B
  float* out = (float*)d_out;

  ge2e_pre<<<1024, 192, 0, stream>>>(dv, (unsigned int*)a8, (unsigned int*)c8,
                                     simown, rowsum, out);
  ge2e_gemm<<<1280, 256, 0, stream>>>(a8, c8, simown, wp, rowsum);
  ge2e_final<<<40, 256, 0, stream>>>(rowsum, simown, wp, out);
}

// Round 7
// 47.019 us; speedup vs baseline: 1.6818x; 1.6818x over previous
//
#include <hip/hip_runtime.h>
#include <hip/hip_bf16.h>

#define EPS 1e-6f

typedef __attribute__((ext_vector_type(4))) float f32x4;

// pack 4 floats into 4 fp8-e4m3 bytes (k-order: x->byte0 .. w->byte3)
__device__ inline unsigned int pack_fp8x4(float x, float y, float z, float w) {
  int r = 0;
  r = __builtin_amdgcn_cvt_pk_fp8_f32(x, y, r, false);  // bytes 0,1
  r = __builtin_amdgcn_cvt_pk_fp8_f32(z, w, r, true);   // bytes 2,3
  return (unsigned int)r;
}

// ---------------------------------------------------------------------------
// Kernel A: per-speaker precompute (192 threads, float4-vectorized).
// Writes: a8[i][d] = fp8e4m3(dvec[i][d]/||dvec_i||)      (10240 x 768, 7.9 MB)
//         c8[n][d] = fp8e4m3(ctrd[n][d]/||ctrd_n||)      (1024 x 768)
//         simown[i] = fp32 cosine(dvec_i, excl-centroid) (10240, exact fp32)
// Also zeroes rowsum[10240] and out[0].  (verified in round 6)
// ---------------------------------------------------------------------------
__global__ void __launch_bounds__(192) ge2e_pre(
    const float* __restrict__ dv, unsigned int* __restrict__ a8u,
    unsigned int* __restrict__ c8u, float* __restrict__ simown,
    float* __restrict__ rowsum, float* __restrict__ out) {
  const int n = blockIdx.x, t = threadIdx.x;  // t in [0,192): owns dims 4t..4t+3
  if (n == 0 && t == 0) out[0] = 0.f;  // consumed by ge2e_final (stream-ordered)
  const float* base = dv + (size_t)n * 7680;
  float4 v[10];
  float4 s4 = make_float4(0.f, 0.f, 0.f, 0.f);
#pragma unroll
  for (int m = 0; m < 10; ++m) {
    v[m] = *reinterpret_cast<const float4*>(&base[m * 768 + 4 * t]);
    s4.x += v[m].x; s4.y += v[m].y; s4.z += v[m].z; s4.w += v[m].w;
  }
  float part[21];
#pragma unroll
  for (int m = 0; m < 10; ++m) {
    part[m]      = v[m].x * s4.x + v[m].y * s4.y + v[m].z * s4.z + v[m].w * s4.w;
    part[10 + m] = v[m].x * v[m].x + v[m].y * v[m].y + v[m].z * v[m].z + v[m].w * v[m].w;
  }
  part[20] = s4.x * s4.x + s4.y * s4.y + s4.z * s4.z + s4.w * s4.w;
#pragma unroll
  for (int k = 0; k < 21; ++k) {
#pragma unroll
    for (int off = 32; off >= 1; off >>= 1) part[k] += __shfl_xor(part[k], off);
  }
  __shared__ float red[3][21];
  __shared__ float bc[21];
  const int lane = t & 63, wid = t >> 6;
  if (lane == 0) {
#pragma unroll
    for (int k = 0; k < 21; ++k) red[wid][k] = part[k];
  }
  __syncthreads();
  if (t < 21) bc[t] = red[0][t] + red[1][t] + red[2][t];
  __syncthreads();
  const float ss = bc[20];
  // centroid = sums/10; cnorm = max(|ctrd|,eps) -> normalize sums by max(|sums|,10eps)
  const float rc = 1.0f / fmaxf(sqrtf(ss), 10.0f * EPS);
  c8u[n * 192 + t] = pack_fp8x4(s4.x * rc, s4.y * rc, s4.z * rc, s4.w * rc);
#pragma unroll
  for (int m = 0; m < 10; ++m) {
    float rd = 1.0f / fmaxf(sqrtf(bc[10 + m]), EPS);
    a8u[(size_t)(n * 10 + m) * 192 + t] =
        pack_fp8x4(v[m].x * rd, v[m].y * rd, v[m].z * rd, v[m].w * rd);
  }
  if (t < 10) {
    float dot = bc[t], sq = bc[10 + t];
    float dn = fmaxf(sqrtf(sq), EPS);
    float en = fmaxf(sqrtf(fmaxf(ss - 2.f * dot + sq, 0.f)) * (1.0f / 9.0f), EPS);
    simown[n * 10 + t] = ((dot - sq) * (1.0f / 9.0f)) / (dn * en);
    rowsum[n * 10 + t] = 0.f;  // accumulated by ge2e_gemm atomics
  }
}

// ---------------------------------------------------------------------------
// Kernel B: fp8 MFMA GEMM (10240x1024x768) fused with diagonal replacement
// and direct exp-sum accumulation.
// Round-7 structure: round-5's PROVEN schedule (depth-1 prefetch, one
// vmcnt(0)+s_barrier per K-step, 64x128 tile, 4 waves 2x2, 1280 blocks = 5
// blocks/CU, bijective XCD swizzle), but:
//   * dtype fp8-e4m3 via NON-scaled mfma_f32_16x16x32_fp8_fp8 (i64 operands,
//     2 VGPR/frag -- no round-6 spill risk; same rate as bf16 but HALF the
//     staging bytes: L2->LDS traffic 369 -> 185 MB)
//   * BK=64 (12 K-steps, half the barrier crossings), LDS K-half-major:
//     As[buf][half][64][32B], Bs[buf][half][128][32B]; 24 KB dbuf -> 5/CU.
// ---------------------------------------------------------------------------
__global__ void __launch_bounds__(256, 5) ge2e_gemm(
    const unsigned char* __restrict__ a8, const unsigned char* __restrict__ c8,
    const float* __restrict__ simown, const float* __restrict__ wp,
    float* __restrict__ rowsum) {
  __shared__ unsigned char As[2][2][64 * 32];    // [buf][half] 2 KB each
  __shared__ unsigned char Bs[2][2][128 * 32];   // [buf][half] 4 KB each
  const int t = threadIdx.x;
  const int lane = t & 63, wid = t >> 6;
  const int bx = blockIdx.x;
  const int wg = (bx & 7) * 160 + (bx >> 3);  // bijective XCD swizzle
  const int rb = wg >> 3, cb = wg & 7;
  const int row0 = rb * 64, col0 = cb * 128;
  const int wr = wid >> 1, wc = wid & 1;       // wave tile: 32 rows x 64 cols
  const int l15 = lane & 15, lg = lane >> 4;

  f32x4 acc[2][4];
#pragma unroll
  for (int i = 0; i < 2; ++i)
#pragma unroll
    for (int j = 0; j < 4; ++j) acc[i][j] = (f32x4){0.f, 0.f, 0.f, 0.f};

  // Stage A (4 KB = 4 segs) + B (8 KB = 8 segs) for K-slab kk; 12 segs of
  // 1 KB (64 lanes x 16 B), 3 per wave. LDS layout is linear in chunk index:
  // A chunk c: half = c>>7, row = (c>>1)&63, k16 = c&1
  //   -> global k-byte = kk + half*32 + k16*16 of row row0+row.
  // B chunk c: half = c>>8, row = (c>>1)&127, k16 = c&1.
  auto STAGE = [&](int buf, int kk) {
#pragma unroll
    for (int jj = 0; jj < 3; ++jj) {
      const int s = wid * 3 + jj;
      if (s < 4) {
        const int c = s * 64 + lane;
        const int half = c >> 7, row = (c >> 1) & 63, k16 = c & 1;
        const unsigned char* src =
            a8 + (size_t)(row0 + row) * 768 + kk + half * 32 + k16 * 16;
        unsigned char* dst = &As[buf][0][0] + s * 1024;  // wave-uniform base
        __builtin_amdgcn_global_load_lds(
            (const __attribute__((address_space(1))) unsigned int*)src,
            (__attribute__((address_space(3))) unsigned int*)dst, 16, 0, 0);
      } else {
        const int c = (s - 4) * 64 + lane;
        const int half = c >> 8, row = (c >> 1) & 127, k16 = c & 1;
        const unsigned char* src =
            c8 + (size_t)(col0 + row) * 768 + kk + half * 32 + k16 * 16;
        unsigned char* dst = &Bs[buf][0][0] + (s - 4) * 1024;
        __builtin_amdgcn_global_load_lds(
            (const __attribute__((address_space(1))) unsigned int*)src,
            (__attribute__((address_space(3))) unsigned int*)dst, 16, 0, 0);
      }
    }
  };
  // frag for (row, half): 8 fp8 k-elems at k = half*32 + lg*8 (i64 operand)
  auto COMPUTE = [&](int buf) {
    long long af[2][2], bq[4][2];
#pragma unroll
    for (int i = 0; i < 2; ++i)
#pragma unroll
      for (int h = 0; h < 2; ++h)
        af[i][h] = *(const long long*)&As[buf][h][(wr * 32 + i * 16 + l15) * 32 + lg * 8];
#pragma unroll
    for (int j = 0; j < 4; ++j)
#pragma unroll
      for (int h = 0; h < 2; ++h)
        bq[j][h] = *(const long long*)&Bs[buf][h][(wc * 64 + j * 16 + l15) * 32 + lg * 8];
#pragma unroll
    for (int h = 0; h < 2; ++h)
#pragma unroll
      for (int i = 0; i < 2; ++i)
#pragma unroll
        for (int j = 0; j < 4; ++j)
          acc[i][j] = __builtin_amdgcn_mfma_f32_16x16x32_fp8_fp8(
              af[i][h], bq[j][h], acc[i][j], 0, 0, 0);
  };

  // prologue
  STAGE(0, 0);
  asm volatile("s_waitcnt vmcnt(0)" ::: "memory");
  __builtin_amdgcn_s_barrier();
  int cur = 0;
  for (int tt = 0; tt < 11; ++tt) {   // 12 K-slabs of 64
    STAGE(cur ^ 1, (tt + 1) * 64);
    COMPUTE(cur);  // lgkmcnt deps force ds_reads done before barrier
    asm volatile("s_waitcnt vmcnt(0)" ::: "memory");
    __builtin_amdgcn_s_barrier();
    cur ^= 1;
  }
  COMPUTE(cur);

  // Epilogue: vv = w*cos (diagonal: fp32 sim_own); rowsum[grow] += sum_j exp(vv)
  // |vv| <= ~10.1 -> exp fp32-safe without max subtraction; bias b cancels.
  const float wv = wp[0];
  const int R0 = row0 + wr * 32, C0 = col0 + wc * 64;
#pragma unroll
  for (int i = 0; i < 2; ++i) {
#pragma unroll
    for (int r = 0; r < 4; ++r) {
      const int grow = R0 + i * 16 + lg * 4 + r;
      const int ownc = grow / 10;  // own speaker column
      float sm = 0.f;
#pragma unroll
      for (int j = 0; j < 4; ++j) {
        const int gcol = C0 + j * 16 + l15;
        float vv = wv * acc[i][j][r];
        if (gcol == ownc) vv = wv * simown[grow];
        sm += __expf(vv);
      }
#pragma unroll
      for (int off = 1; off < 16; off <<= 1) sm += __shfl_xor(sm, off, 16);
      if (l15 == 0) atomicAdd(&rowsum[grow], sm);
    }
  }
}

// ---------------------------------------------------------------------------
// Kernel C: loss_i = log(rowsum_i) - w*simown_i; sum over 10240 into d_out.
// ---------------------------------------------------------------------------
__global__ void __launch_bounds__(256) ge2e_final(
    const float* __restrict__ rowsum, const float* __restrict__ simown,
    const float* __restrict__ wp, float* __restrict__ out) {
  const int i = blockIdx.x * 256 + threadIdx.x;  // 0..10239
  const float wv = wp[0];
  float loss = logf(rowsum[i]) - wv * simown[i];
#pragma unroll
  for (int off = 32; off >= 1; off >>= 1) loss += __shfl_xor(loss, off);
  __shared__ float red[4];
  const int lane = threadIdx.x & 63, wid = threadIdx.x >> 6;
  if (lane == 0) red[wid] = loss;
  __syncthreads();
  if (threadIdx.x == 0) atomicAdd(out, red[0] + red[1] + red[2] + red[3]);
}

extern "C" void kernel_launch(void* const* d_in, const int* in_sizes, int n_in,
                              void* d_out, int out_size, void* d_ws, size_t ws_size,
                              hipStream_t stream) {
  (void)in_sizes; (void)n_in; (void)out_size; (void)ws_size;
  const float* dv = (const float*)d_in[0];
  const float* wp = (const float*)d_in[1];
  // d_in[2] (bias b) cancels exactly in -log_softmax[own]; unused.

  unsigned char* a8 = (unsigned char*)d_ws;                         // 7,864,320 B
  unsigned char* c8 = (unsigned char*)d_ws + 7864320;               //   786,432 B
  float* simown = (float*)((char*)d_ws + 8650752);                  //    40,960 B
  float* rowsum = (float*)((char*)d_ws + 8691712);                  //    40,960 B
  float* out = (float*)d_out;

  ge2e_pre<<<1024, 192, 0, stream>>>(dv, (unsigned int*)a8, (unsigned int*)c8,
                                     simown, rowsum, out);
  ge2e_gemm<<<1280, 256, 0, stream>>>(a8, c8, simown, wp, rowsum);
  ge2e_final<<<40, 256, 0, stream>>>(rowsum, simown, wp, out);
}